// Round 3
// baseline (131.823 us; speedup 1.0000x reference)
//
#include <hip/hip_runtime.h>

#define BB 2
#define NN 512
#define INF 10

static __device__ __forceinline__ float dot4(float4 w, float4 v, float acc) {
    acc = fmaf(w.x, v.x, acc);
    acc = fmaf(w.y, v.y, acc);
    acc = fmaf(w.z, v.z, acc);
    acc = fmaf(w.w, v.w, acc);
    return acc;
}

// Kernel 1: per-point MLP chain (10->128->128->64) + projections to ha[256], hb[256]+bp0.
// 256 blocks x 256 threads, 4 points per block. Outputs f-contiguous: haT[point][f].
// Also initializes d_out to bp1 (so k_outer can atomicAdd partials).
__global__ __launch_bounds__(256) void k_points(
    const float* __restrict__ x,
    const float* __restrict__ Ws0, const float* __restrict__ bs0,
    const float* __restrict__ Ws1, const float* __restrict__ bs1,
    const float* __restrict__ Ws2, const float* __restrict__ bs2,
    const float* __restrict__ Wp0, const float* __restrict__ bp0,
    float* __restrict__ haT, float* __restrict__ hbT,
    float* __restrict__ out, const float* __restrict__ bp1)
{
    __shared__ __align__(16) float xs[4][INF];
    __shared__ __align__(16) float u0s[4][128];
    __shared__ __align__(16) float u1s[4][128];
    __shared__ __align__(16) float u2s[4][64];

    const int t  = threadIdx.x;
    const int p0 = blockIdx.x * 4;   // flat point index b*N+n (4 points, same batch)

    // init out = bp1 (2*512*512 floats = 131072 float4; 65536 threads x 2)
    {
        const float bv = bp1[0];
        const float4 b4 = { bv, bv, bv, bv };
        float4* o4 = (float4*)out;
        const int gt = blockIdx.x * 256 + t;
        o4[gt * 2 + 0] = b4;
        o4[gt * 2 + 1] = b4;
    }

    // load x for 4 points
    if (t < 4 * INF) {
        int p = t / INF, c = t % INF;
        xs[p][c] = x[(p0 + p) * INF + c];
    }
    __syncthreads();

    // layer 0: 10 -> 128 (thread t: f = t&127, two points ph*2+{0,1})
    {
        const int f = t & 127, ph = t >> 7;
        float a0 = bs0[f], a1 = a0;
        #pragma unroll
        for (int c = 0; c < INF; ++c) {
            float w = Ws0[f * INF + c];
            a0 = fmaf(w, xs[ph * 2 + 0][c], a0);
            a1 = fmaf(w, xs[ph * 2 + 1][c], a1);
        }
        u0s[ph * 2 + 0][f] = fmaxf(a0, 0.f);
        u0s[ph * 2 + 1][f] = fmaxf(a1, 0.f);
    }
    __syncthreads();

    // layer 1: 128 -> 128
    {
        const int f = t & 127, ph = t >> 7;
        float a0 = bs1[f], a1 = a0;
        const float4* wv = (const float4*)(Ws1 + f * 128);
        #pragma unroll 8
        for (int c4 = 0; c4 < 32; ++c4) {
            float4 w  = wv[c4];
            float4 x0 = *(const float4*)&u0s[ph * 2 + 0][c4 * 4];
            float4 x1 = *(const float4*)&u0s[ph * 2 + 1][c4 * 4];
            a0 = dot4(w, x0, a0);
            a1 = dot4(w, x1, a1);
        }
        u1s[ph * 2 + 0][f] = fmaxf(a0, 0.f);
        u1s[ph * 2 + 1][f] = fmaxf(a1, 0.f);
    }
    __syncthreads();

    // layer 2: 128 -> 64 (thread t: f = t&63, point p = t>>6)
    {
        const int f = t & 63, p = t >> 6;
        float a = bs2[f];
        const float4* wv = (const float4*)(Ws2 + f * 128);
        #pragma unroll 8
        for (int c4 = 0; c4 < 32; ++c4) {
            float4 w  = wv[c4];
            float4 xv = *(const float4*)&u1s[p][c4 * 4];
            a = dot4(w, xv, a);
        }
        u2s[p][f] = fmaxf(a, 0.f);
    }
    __syncthreads();

    // projection: f = t (0..255); ha[f] = Wa[f,:]@u2, hb[f] = Wb[f,:]@u2 + bp0[f], 4 points each
    {
        const int f = t;
        float ah[4], bh[4];
        const float bb = bp0[f];
        #pragma unroll
        for (int p = 0; p < 4; ++p) { ah[p] = 0.f; bh[p] = bb; }
        const float4* wv = (const float4*)(Wp0 + f * 128);
        #pragma unroll 4
        for (int c4 = 0; c4 < 16; ++c4) {
            float4 wa = wv[c4];
            float4 wb = wv[16 + c4];
            #pragma unroll
            for (int p = 0; p < 4; ++p) {
                float4 u = *(const float4*)&u2s[p][c4 * 4];
                ah[p] = dot4(wa, u, ah[p]);
                bh[p] = dot4(wb, u, bh[p]);
            }
        }
        #pragma unroll
        for (int p = 0; p < 4; ++p) {
            haT[(size_t)(p0 + p) * 256 + f] = ah[p];
            hbT[(size_t)(p0 + p) * 256 + f] = bh[p];
        }
    }
}

// Kernel 2: out[b,i,j] += sum_{f in chunk} w[f]*relu(ha[b,f,j] + hbc[b,f,i])
// grid (8,8,8): z = b*4+fh. 64x64 output tile, f-chunk of 64 per block.
// 256 threads: 4 waves as 2x2 (32x32 regions), lane = 8x8, 4x4 register tile.
// LDS tiles [64 rows][16 units of 16B], unit XOR-swizzled by (row>>2)&7 -> conflict-free.
__global__ __launch_bounds__(256) void k_outer(
    const float* __restrict__ haT, const float* __restrict__ hbT,
    const float* __restrict__ Wp1, float* __restrict__ out)
{
    __shared__ __align__(16) float sA[64 * 64];  // ha, local j rows
    __shared__ __align__(16) float sB[64 * 64];  // hb(+bp0), local i rows
    __shared__ __align__(16) float sW[64];

    const int t  = threadIdx.x;
    const int jb = blockIdx.x * 64;
    const int ib = blockIdx.y * 64;
    const int b  = blockIdx.z >> 2;
    const int f0 = (blockIdx.z & 3) * 64;   // f-chunk base

    // stage: 64 rows x 64 floats each array; XOR-swizzled 16B units
    #pragma unroll
    for (int k = 0; k < 4; ++k) {
        const int u  = t + 256 * k;        // 0..1023
        const int r  = u >> 4;             // row 0..63
        const int f4 = u & 15;             // 16B unit 0..15
        const int fs = f4 ^ ((r >> 2) & 7);
        float4 va = ((const float4*)(haT + ((size_t)(b * NN + jb + r)) * 256 + f0))[f4];
        float4 vb = ((const float4*)(hbT + ((size_t)(b * NN + ib + r)) * 256 + f0))[f4];
        *(float4*)&sA[r * 64 + fs * 4] = va;
        *(float4*)&sB[r * 64 + fs * 4] = vb;
    }
    if (t < 16) *(float4*)&sW[t * 4] = ((const float4*)(Wp1 + f0))[t];
    __syncthreads();

    const int lane = t & 63, wid = t >> 6;
    const int li = lane >> 3, lj = lane & 7;
    const int wr = wid >> 1, wc = wid & 1;
    const int i0 = wr * 32 + li * 4;       // local i of acc row 0
    const int j0 = wc * 32 + lj * 4;       // local j of acc col 0

    // byte-offset XOR values: for rows j0..j0+3, (row>>2)&7 == lj; for i0..i0+3 == li
    const int swa = lj << 4;
    const int swb = li << 4;
    const char* baseA = (const char*)&sA[j0 * 64];   // row stride 256 B
    const char* baseB = (const char*)&sB[i0 * 64];

    float acc[4][4] = {{0.f}};

    #pragma unroll
    for (int g = 0; g < 16; ++g) {
        const float4 w = *(const float4*)&sW[g * 4];
        const int xa = (g << 4) ^ swa;
        const int xb = (g << 4) ^ swb;
        float4 av[4], bv[4];
        #pragma unroll
        for (int k = 0; k < 4; ++k) {
            av[k] = *(const float4*)(baseA + k * 256 + xa);
            bv[k] = *(const float4*)(baseB + k * 256 + xb);
        }
        #pragma unroll
        for (int di = 0; di < 4; ++di) {
            #pragma unroll
            for (int dj = 0; dj < 4; ++dj) {
                acc[di][dj] = fmaf(w.x, fmaxf(av[dj].x + bv[di].x, 0.f), acc[di][dj]);
                acc[di][dj] = fmaf(w.y, fmaxf(av[dj].y + bv[di].y, 0.f), acc[di][dj]);
                acc[di][dj] = fmaf(w.z, fmaxf(av[dj].z + bv[di].z, 0.f), acc[di][dj]);
                acc[di][dj] = fmaf(w.w, fmaxf(av[dj].w + bv[di].w, 0.f), acc[di][dj]);
            }
        }
    }

    float* o = out + (size_t)b * NN * NN;
    const int gi = ib + i0, gj = jb + j0;
    #pragma unroll
    for (int di = 0; di < 4; ++di) {
        #pragma unroll
        for (int dj = 0; dj < 4; ++dj) {
            atomicAdd(&o[(size_t)(gi + di) * NN + (gj + dj)], acc[di][dj]);
        }
    }
}

extern "C" void kernel_launch(void* const* d_in, const int* in_sizes, int n_in,
                              void* d_out, int out_size, void* d_ws, size_t ws_size,
                              hipStream_t stream) {
    const float* x   = (const float*)d_in[0];
    const float* Ws0 = (const float*)d_in[1];
    const float* bs0 = (const float*)d_in[2];
    const float* Ws1 = (const float*)d_in[3];
    const float* bs1 = (const float*)d_in[4];
    const float* Ws2 = (const float*)d_in[5];
    const float* bs2 = (const float*)d_in[6];
    const float* Wp0 = (const float*)d_in[7];
    const float* bp0 = (const float*)d_in[8];
    const float* Wp1 = (const float*)d_in[9];
    const float* bp1 = (const float*)d_in[10];

    float* haT = (float*)d_ws;                       // [B*N][256]
    float* hbT = haT + (size_t)BB * NN * 256;        // [B*N][256]

    k_points<<<dim3(BB * NN / 4), dim3(256), 0, stream>>>(
        x, Ws0, bs0, Ws1, bs1, Ws2, bs2, Wp0, bp0, haT, hbT, (float*)d_out, bp1);

    k_outer<<<dim3(NN / 64, NN / 64, BB * 4), dim3(256), 0, stream>>>(
        haT, hbT, Wp1, (float*)d_out);
}